// Round 12
// baseline (143.319 us; speedup 1.0000x reference)
//
#include <hip/hip_runtime.h>
#include <float.h>
#include <stdint.h>

// Chamfer distance via MFMA (bf16 hi/lo compensated split), round 12.
// d[n][m] = ||t_m||^2 - 2 q_n . t_m  + ||q_n||^2 (added in epilogue)
// One mfma_f32_32x32x16_bf16 computes a 32q x 32t tile of (tt - 2q.t):
//   A k-slots (query row, c = -2q): [chx chy chz clx cly clz chx chy |
//                                    chz 1 1 clx cly clz 0 0]
//   B k-slots (target col):         [bhx bhy bhz bhx bhy bhz blx bly |
//                                    blz tth ttl blx bly blz 0 0]
// B fragments prepacked by prep_kernel into ws (8 MB): H0 region = lanes
// 0-31 (k=0..7), H1 region = lanes 32-63 (k=8..15).
// R12 vs R7 (47.6us, ~2.5 waves/SIMD): ONE A-block per wave (32 queries,
// 16 accumulators) halves live register state (~115 -> ~80 regs) ->
// ~6 waves/SIMD; grid 2048 (8 blocks/CU). Same total MFMA count. Block
// covers ALL targets for its 128 queries -> final values -> block-sum +
// one atomicAdd (reduce kernel eliminated; 2 dispatches total).
// Proven-verbatim pieces: A/B packing, fminf-pair fold (v_min3), shfl16
// prefold + [128][17] LDS transpose, bijective XCD swizzle.
// No reg-staging / no double-buffer (R6/R10 spill lesson).

typedef short bf16x8 __attribute__((ext_vector_type(8)));
typedef float f32x16 __attribute__((ext_vector_type(16)));

#define BLK 256
#define ONE_BF 0x3F80u

__device__ __forceinline__ uint32_t bf16_rne(float f) {
    uint32_t u = __builtin_bit_cast(uint32_t, f);
    return (u + 0x7FFFu + ((u >> 16) & 1u)) >> 16;
}
__device__ __forceinline__ float bf16f(uint32_t h) {
    return __builtin_bit_cast(float, h << 16);
}

// ---- prep: 262144 points (arr0 = x, arr1 = recon), 16B H0 + 16B H1 each.
// Also zeroes the output accumulator (stream-ordered before main).
__global__ __launch_bounds__(BLK)
void prep_kernel(const float* __restrict__ x, const float* __restrict__ recon,
                 uint32_t* __restrict__ ws, float* __restrict__ out)
{
    int tid = blockIdx.x * BLK + threadIdx.x;     // 0..262143
    if (tid == 0) out[0] = 0.0f;
    int arr = tid >> 17;
    int p   = tid & 131071;
    const float* s = arr ? recon : x;
    float a = s[3 * p], b = s[3 * p + 1], c = s[3 * p + 2];
    uint32_t hx = bf16_rne(a), hy = bf16_rne(b), hz = bf16_rne(c);
    uint32_t lx = bf16_rne(a - bf16f(hx));
    uint32_t ly = bf16_rne(b - bf16f(hy));
    uint32_t lz = bf16_rne(c - bf16f(hz));
    float tt = a * a + b * b + c * c;
    uint32_t th = bf16_rne(tt);
    uint32_t tl = bf16_rne(tt - bf16f(th));
    uint4 H0 = make_uint4(hx | (hy << 16), hz | (hx << 16),
                          hy | (hz << 16), lx | (ly << 16));
    uint4 H1 = make_uint4(lz | (th << 16), tl | (lx << 16),
                          ly | (lz << 16), 0u);
    ((uint4*)ws)[tid]          = H0;
    ((uint4*)ws)[262144 + tid] = H1;
}

// ---- main: 2048 blocks (XCD-swizzled; dir x 32 b x 32 qb), 4 waves.
// Each wave: ONE 32-query A-block x all 4096 targets. Block covers 128
// queries completely -> block-sum -> one atomicAdd. 8.7 KB LDS.
__global__ __launch_bounds__(BLK)
void chamfer_mfma(const float* __restrict__ x, const float* __restrict__ recon,
                  const uint32_t* __restrict__ ws, float* __restrict__ out,
                  float scale)
{
    // XCD-aware bijective swizzle (2048 % 8 == 0): CPX = 256.
    int idx = blockIdx.x;
    int swz = (idx & 7) * 256 + (idx >> 3);
    int qb  = swz & 31;                           // 32 query blocks of 128
    int b   = (swz >> 5) & 31;
    int dir = swz >> 10;

    const float* qsrc = dir ? recon : x;          // queries
    const int arrT = dir ? 0 : 1;                 // targets = other array

    const int tid  = threadIdx.x;
    const int wave = tid >> 6;
    const int lane = tid & 63;
    const int l31  = lane & 31;
    const int lh   = lane >> 5;

    __shared__ float lmin[128][17];
    __shared__ float red[2];

    // A fragment (R7-verbatim packing): row = l31 of this wave's 32 queries.
    bf16x8 A0;
    {
        int n0 = qb * 128 + wave * 32 + l31;
        const float* qp = qsrc + ((size_t)b * 4096 + n0) * 3;
        float cx = -2.f * qp[0], cy = -2.f * qp[1], cz = -2.f * qp[2];
        uint32_t hx = bf16_rne(cx), hy = bf16_rne(cy), hz = bf16_rne(cz);
        uint32_t lx = bf16_rne(cx - bf16f(hx));
        uint32_t ly = bf16_rne(cy - bf16f(hy));
        uint32_t lz = bf16_rne(cz - bf16f(hz));
        uint32_t w0, w1, w2, w3;
        if (lh == 0) {
            w0 = hx | (hy << 16); w1 = hz | (lx << 16);
            w2 = ly | (lz << 16); w3 = hx | (hy << 16);
        } else {
            w0 = hz | (ONE_BF << 16); w1 = ONE_BF | (lx << 16);
            w2 = ly | (lz << 16);     w3 = 0u;
        }
        union { uint4 u; bf16x8 v; } cvt;
        cvt.u = make_uint4(w0, w1, w2, w3);
        A0 = cvt.v;
    }

    f32x16 zc = {0,0,0,0,0,0,0,0,0,0,0,0,0,0,0,0};
    float rmn[16];
    #pragma unroll
    for (int j = 0; j < 16; ++j) rmn[j] = FLT_MAX;

    // B-fragment stream: lane half picks H0/H1 region; col = l31.
    const uint4* rp = (const uint4*)ws
        + (size_t)lh * 262144 + (size_t)arrT * 131072 + (size_t)b * 4096 + l31;

    // 64 iters x 2 target-tiles: short chain (2 loads -> 2 MFMA -> 16 min3).
    for (int it = 0; it < 64; ++it) {
        union BU { uint4 u; bf16x8 v; } B0, B1;
        B0.u = rp[0];
        B1.u = rp[32];
        rp += 64;
        f32x16 d0 = __builtin_amdgcn_mfma_f32_32x32x16_bf16(A0, B0.v, zc, 0, 0, 0);
        f32x16 d1 = __builtin_amdgcn_mfma_f32_32x32x16_bf16(A0, B1.v, zc, 0, 0, 0);
        #pragma unroll
        for (int j = 0; j < 16; ++j)
            rmn[j] = fminf(rmn[j], fminf(d0[j], d1[j]));
    }

    // Epilogue: shfl16 col prefold + half-width LDS transpose (R9-proven).
    #pragma unroll
    for (int j = 0; j < 16; ++j) {
        int rl = (j & 3) + 8 * (j >> 2) + 4 * lh;  // verified 32x32 C/D row
        float a = fminf(rmn[j], __shfl_xor(rmn[j], 16, 64));
        // lanes l31 and l31^16 hold identical values; same-addr dup write.
        lmin[wave * 32 + rl][l31 & 15] = a;
    }
    __syncthreads();

    // tid < 128: one query row each -> min over 16 cols, + ||q||^2.
    float v = 0.0f;
    if (tid < 128) {
        float m = lmin[tid][0];
        #pragma unroll
        for (int c = 1; c < 16; ++c) m = fminf(m, lmin[tid][c]);
        const float* qp = qsrc + ((size_t)b * 4096 + qb * 128 + tid) * 3;
        v = m + qp[0] * qp[0] + qp[1] * qp[1] + qp[2] * qp[2];
    }

    // Block sum (waves 0,1 carry data; 2,3 contribute zeros) -> one atomic.
    #pragma unroll
    for (int off = 32; off > 0; off >>= 1)
        v += __shfl_down(v, off, 64);
    if (lane == 0 && wave < 2) red[wave] = v;
    __syncthreads();
    if (tid == 0)
        atomicAdd(out, (red[0] + red[1]) * scale);
}

extern "C" void kernel_launch(void* const* d_in, const int* in_sizes, int n_in,
                              void* d_out, int out_size, void* d_ws, size_t ws_size,
                              hipStream_t stream) {
    const float* x     = (const float*)d_in[0];
    const float* recon = (const float*)d_in[1];
    float* out = (float*)d_out;
    uint32_t* ws = (uint32_t*)d_ws;               // needs 8 MiB

    const float scale = 1.0f / (32.0f * 4096.0f);

    prep_kernel<<<1024, BLK, 0, stream>>>(x, recon, ws, out);
    chamfer_mfma<<<2048, BLK, 0, stream>>>(x, recon, ws, out, scale);
}